// Round 12
// baseline (2738.286 us; speedup 1.0000x reference)
//
#include <hip/hip_runtime.h>
#include <stdint.h>

#define S_LEN 512
#define BATCH 64
#define INSZ  256
#define HID   1024
#define BH    (BATCH*HID)          // 65536
#define NPIPE 8
#define ROWSP 8                    // batch rows per pipeline
#define NCG   32                   // WGs per pipeline
// LDS: 64KB Wh-hi + 64KB Wh-lo + 2x8KB reduce (dbuf)
#define SMEM_BYTES (131072 + 16384)
// ws dword map:
//  [0,1024)  flags (non-SPLIT fallback only): flag(pipe,cg) at
//            dword pipe*128 + (cg>>3)*32 + (cg&7). gbar at ws[8].
//  byte 4096+: bf16 planes. chunk idx (pipe*2+buf)*2+plane ; lo = hi+PLANE_STRIDE
#define WS_PLANES_OFF 4096
#define PLANE_STRIDE (ROWSP*HID)   // 8192 shorts
#define WS_NEEDED (WS_PLANES_OFF + NPIPE*2*2*PLANE_STRIDE*2)   // 528384 B
#define FLAG_IDX(p, c) ((p)*128 + ((c)>>3)*32 + ((c)&7))

typedef __attribute__((ext_vector_type(8))) short short8;   // 8 bf16
typedef __attribute__((ext_vector_type(4))) short short4v;
typedef __attribute__((ext_vector_type(4))) float f32x4;
typedef __attribute__((ext_vector_type(4))) float f4;
typedef __attribute__((ext_vector_type(4))) unsigned int u32x4;

__device__ __forceinline__ uint32_t bf16_rne(float x) {
  uint32_t u = __float_as_uint(x);
  return (u + 0x7fffu + ((u >> 16) & 1u)) >> 16;
}
__device__ __forceinline__ void cvt_pair(float v, short& h, short& l) {
  uint32_t hb = bf16_rne(v);
  float hf = __uint_as_float(hb << 16);
  uint32_t lb = bf16_rne(v - hf);
  h = (short)hb; l = (short)lb;
}
__device__ __forceinline__ void cvt8(f4 a0, f4 a1, short8& hi, short8& lo) {
  #pragma unroll
  for (int e = 0; e < 4; ++e) { short h, l; cvt_pair(a0[e], h, l); hi[e] = h; lo[e] = l; }
  #pragma unroll
  for (int e = 0; e < 4; ++e) { short h, l; cvt_pair(a1[e], h, l); hi[4+e] = h; lo[4+e] = l; }
}

#define MFMA(A, B, C) __builtin_amdgcn_mfma_f32_16x16x32_bf16((A), (B), (C), 0, 0, 0)
#define WAIT_VM0() do { asm volatile("s_waitcnt vmcnt(0)" ::: "memory"); \
                        __builtin_amdgcn_sched_barrier(0); } while (0)

// ---------- LLC-direct (bypass L1+L2, MALL coherence point) helpers ----------
__device__ __forceinline__ void llc_load_f4(f4& d, const float* p) {
  asm volatile("global_load_dwordx4 %0, %1, off sc0 sc1" : "=v"(d) : "v"(p) : "memory");
}
__device__ __forceinline__ void llc_load_s8(short8& d, const uint16_t* p) {
  asm volatile("global_load_dwordx4 %0, %1, off sc0 sc1" : "=v"(d) : "v"(p) : "memory");
}
__device__ __forceinline__ void llc_store_f4(float* p, f4 v) {
  asm volatile("global_store_dwordx4 %0, %1, off sc0 sc1" :: "v"(p), "v"(v) : "memory");
}
__device__ __forceinline__ void llc_store_s4(uint16_t* p, short4v v) {
  asm volatile("global_store_dwordx2 %0, %1, off sc0 sc1" :: "v"(p), "v"(v) : "memory");
}
__device__ __forceinline__ void llc_store_u16(uint16_t* p, uint32_t v) {
  asm volatile("global_store_short %0, %1, off sc0 sc1" :: "v"(p), "v"(v) : "memory");
}
__device__ __forceinline__ void llc_store_u32(uint32_t* p, uint32_t v) {
  asm volatile("global_store_dword %0, %1, off sc0 sc1" :: "v"(p), "v"(v) : "memory");
}
__device__ __forceinline__ uint32_t poll_min8(const uint32_t* p) {
  u32x4 a, b;
  asm volatile("global_load_dwordx4 %0, %2, off sc0 sc1\n\t"
               "global_load_dwordx4 %1, %2, off offset:16 sc0 sc1\n\t"
               "s_waitcnt vmcnt(0)"
               : "=&v"(a), "=&v"(b) : "v"(p) : "memory");
  uint32_t m = a.x;
  m = a.y < m ? a.y : m;  m = a.z < m ? a.z : m;  m = a.w < m ? a.w : m;
  m = b.x < m ? b.x : m;  m = b.y < m ? b.y : m;  m = b.z < m ? b.z : m;
  m = b.w < m ? b.w : m;
  return m;
}

__global__ void ctrnn_init(uint32_t* ws) {
  const int i = threadIdx.x;
  ws[i] = 0; ws[i + 256] = 0; ws[i + 512] = 0; ws[i + 768] = 0;
}

template<bool SPLIT>
__global__ __launch_bounds__(256, 1)
void ctrnn_main(const float* __restrict__ x,  const float* __restrict__ h0,
                const float* __restrict__ Wx, const float* __restrict__ bx,
                const float* __restrict__ Wh, const float* __restrict__ bh,
                float* __restrict__ out, uint32_t* ws)
{
  extern __shared__ char smem_raw[];
  short* pHi = (short*)smem_raw;             // 64KB
  short* pLo = pHi + 32768;                  // 64KB
  float* red = (float*)(smem_raw + 131072);  // 2 x 8KB (dbuf by t&1)

  const int tid  = threadIdx.x;
  const int wg   = blockIdx.x;
  const int lane = tid & 63;
  const int wave = tid >> 6;
  const int l15  = lane & 15;
  const int kg   = lane >> 4;

  // ======================= phase 0: xproj = x @ Wx^T + bx =======================
  for (int tt = 0; tt < 2; ++tt) {
    const int t = wg * 2 + tt;
    if (tt) __syncthreads();
    { // stage x[t] (64x256 f32) into swizzled split hi/lo bf16 planes
      const float* xt = x + (size_t)t * (BATCH * INSZ);
      #pragma unroll
      for (int it = 0; it < 16; ++it) {
        const int flat4 = (it * 256 + tid) * 4;
        const int b = flat4 >> 8;
        const int k = flat4 & 255;
        f4 v = *(const f4*)(xt + b * INSZ + k);
        short4v hv, lv;
        #pragma unroll
        for (int e = 0; e < 4; ++e) { short h, l; cvt_pair(v[e], h, l); hv[e] = h; lv[e] = l; }
        const int si = b * 256 + (k ^ ((b & 7) << 3));
        *(short4v*)(pHi + si) = hv;
        *(short4v*)(pLo + si) = lv;
      }
    }
    __syncthreads();
    for (int ntl = 0; ntl < 16; ++ntl) {
      const int nt = wave * 16 + ntl;
      const int nn = nt * 16 + l15;
      f32x4 acc0 = {0,0,0,0}, acc1 = {0,0,0,0}, acc2 = {0,0,0,0}, acc3 = {0,0,0,0};
      #pragma unroll
      for (int kt = 0; kt < 8; ++kt) {
        const int k = kt * 32 + kg * 8;
        const float* wp = Wx + (size_t)nn * INSZ + k;
        short8 bhi8, blo8;
        cvt8(*(const f4*)wp, *(const f4*)(wp + 4), bhi8, blo8);
        const int swz = (l15 & 7) << 3;
        short8 a0h = *(const short8*)(pHi + (     l15) * 256 + (k ^ swz));
        short8 a0l = *(const short8*)(pLo + (     l15) * 256 + (k ^ swz));
        short8 a1h = *(const short8*)(pHi + (16 + l15) * 256 + (k ^ swz));
        short8 a1l = *(const short8*)(pLo + (16 + l15) * 256 + (k ^ swz));
        short8 a2h = *(const short8*)(pHi + (32 + l15) * 256 + (k ^ swz));
        short8 a2l = *(const short8*)(pLo + (32 + l15) * 256 + (k ^ swz));
        short8 a3h = *(const short8*)(pHi + (48 + l15) * 256 + (k ^ swz));
        short8 a3l = *(const short8*)(pLo + (48 + l15) * 256 + (k ^ swz));
        acc0 = MFMA(a0h, bhi8, acc0);
        acc1 = MFMA(a1h, bhi8, acc1);
        acc2 = MFMA(a2h, bhi8, acc2);
        acc3 = MFMA(a3h, bhi8, acc3);
        acc0 = MFMA(a0l, bhi8, acc0);
        acc1 = MFMA(a1l, bhi8, acc1);
        acc2 = MFMA(a2l, bhi8, acc2);
        acc3 = MFMA(a3l, bhi8, acc3);
        acc0 = MFMA(a0h, blo8, acc0);
        acc1 = MFMA(a1h, blo8, acc1);
        acc2 = MFMA(a2h, blo8, acc2);
        acc3 = MFMA(a3h, blo8, acc3);
      }
      const float bxn = bx[nn];
      float* op = out + (size_t)t * BH;
      #pragma unroll
      for (int i = 0; i < 4; ++i) {
        const int b0 = kg * 4 + i;
        op[(size_t)(     b0) * HID + nn] = acc0[i] + bxn;
        op[(size_t)(16 + b0) * HID + nn] = acc1[i] + bxn;
        op[(size_t)(32 + b0) * HID + nn] = acc2[i] + bxn;
        op[(size_t)(48 + b0) * HID + nn] = acc3[i] + bxn;
      }
    }
  }

  // ======================= load Wh slice (32 cols x 1024 K) into LDS =======================
  __syncthreads();
  const int pipe = wg >> 5;             // 0..7  : batch rows [8*pipe, 8*pipe+8)
  const int cg   = wg & 31;             // 0..31 : cols [32*cg, 32*cg+32)
  const int rbase = pipe * ROWSP;
  #pragma unroll
  for (int it = 0; it < 32; ++it) {
    const int flat4 = (it * 256 + tid) * 4;
    const int r = flat4 >> 10;
    const int k = flat4 & 1023;
    f4 w = *(const f4*)(Wh + (size_t)(cg * 32 + r) * HID + k);
    short4v hv, lv;
    #pragma unroll
    for (int e = 0; e < 4; ++e) { short h, l; cvt_pair(w[e], h, l); hv[e] = h; lv[e] = l; }
    const int si = r * 1024 + (k ^ ((r & 7) << 3));
    *(short4v*)(pHi + si) = hv;
    *(short4v*)(pLo + si) = lv;
  }

  uint16_t* planes = (uint16_t*)((char*)ws + WS_PLANES_OFF);
  // chunk base (shorts): ((pipe*2 + buf)*2 + plane) * PLANE_STRIDE ; lo = hi + PLANE_STRIDE

  // pre-stage h0 tile into planes buf=1 (read at t=0) with version bits = 0
  // (cols c&3==1 carry bit0, c&3==3 carry bit1); ordered by the global barrier
  if (SPLIT) {
    const int r = tid >> 5, c = tid & 31;
    const float v = h0[(size_t)(rbase + r) * HID + cg * 32 + c];
    uint32_t hb = bf16_rne(v);
    const bool vb = ((c & 3) == 1) || ((c & 3) == 3);
    if (vb) hb &= ~1u;
    float hf = __uint_as_float(hb << 16);
    uint32_t lb = bf16_rne(v - hf);
    if (vb) lb &= ~1u;
    uint16_t* bH = planes + ((pipe * 2 + 1) * 2 + 0) * PLANE_STRIDE + r * HID + cg * 32 + c;
    llc_store_u16(bH, hb & 0xffffu);
    llc_store_u16(bH + PLANE_STRIDE, lb & 0xffffu);
  }

  // epilogue state (wave 0): lane owns row er, cols [cg*32+4*ejc, +4)
  const int er = lane >> 3, ejc = lane & 7;
  f4 hp = {0,0,0,0}, bhv = {0,0,0,0};
  if (wave == 0) {
    hp  = *(const f4*)(h0 + (size_t)(rbase + er) * HID + cg * 32 + ejc * 4);
    bhv = *(const f4*)(bh + cg * 32 + ejc * 4);
  }

  // drain h0-staging LLC stores from ALL waves before any WG can pass the barrier
  asm volatile("s_waitcnt vmcnt(0)" ::: "memory");
  __syncthreads();

  // ======================= global barrier (release flushes phase-0 stores) ==========
  uint32_t* gbar = ws + 8;
  if (tid == 0) {
    __hip_atomic_fetch_add(gbar, 1u, __ATOMIC_RELEASE, __HIP_MEMORY_SCOPE_AGENT);
    int spins = 0;
    while (__hip_atomic_load(gbar, __ATOMIC_RELAXED, __HIP_MEMORY_SCOPE_AGENT) < 256u) {
      __builtin_amdgcn_s_sleep(8);
      if (++spins > (1 << 20)) break;   // failsafe: wrong answer beats eternal hang
    }
  }
  __syncthreads();
  __builtin_amdgcn_fence(__ATOMIC_ACQUIRE, "agent");

  // ======================= scan =======================
  uint32_t* flags = ws;                               // fallback path only
  uint32_t* myflag = flags + FLAG_IDX(pipe, cg);
  const uint32_t* pollbase = flags + pipe * 128 + wave * 32;

  for (int t = 0; t < S_LEN; ++t) {
    float* op = out + (size_t)t * BH;
    const int buf_r = (t + 1) & 1, buf_w = t & 1;

    // epilogue xproj operand (plain cached load; compiler inserts waitcnt at use)
    f4 xv = {0,0,0,0};
    if (wave == 0)
      xv = *(const f4*)(op + (size_t)(rbase + er) * HID + cg * 32 + ejc * 4);

    short8 ah[8], al[8];
    #pragma unroll
    for (int kk = 0; kk < 8; ++kk) { ah[kk] = (short8)0; al[kk] = (short8)0; }

    if (SPLIT) {
      // ---- NO flag gate: load-and-verify IS the gate (discovery merged into
      // the data RT). Backpressure is the pipe-wide data dependency: a producer
      // can only overwrite buf B at t+1 after verifying ALL step-t planes,
      // which post-dates every pipe WG's reads of buf B at step t.
      const uint16_t* pH = planes + ((pipe * 2 + buf_r) * 2 + 0) * PLANE_STRIDE
                           + l15 * HID + wave * 256 + kg * 8;
      const uint16_t* pL = pH + PLANE_STRIDE;
      const uint32_t vb0 = (uint32_t)(t & 1);
      const uint32_t vb1 = (uint32_t)((t >> 1) & 1);
      int attempts = 0;
      for (;;) {
        if (l15 < 8) {
          #pragma unroll
          for (int kk = 0; kk < 8; ++kk) {
            llc_load_s8(ah[kk], pH + kk * 32);
            llc_load_s8(al[kk], pL + kk * 32);
          }
        }
        WAIT_VM0();
        uint32_t bad = 0;
        if (l15 < 8) {
          #pragma unroll
          for (int kk = 0; kk < 8; ++kk) {
            bad |= ((uint32_t)ah[kk][1] ^ vb0) & 1u;
            bad |= ((uint32_t)ah[kk][3] ^ vb1) & 1u;
            bad |= ((uint32_t)ah[kk][5] ^ vb0) & 1u;
            bad |= ((uint32_t)ah[kk][7] ^ vb1) & 1u;
            bad |= ((uint32_t)al[kk][1] ^ vb0) & 1u;
            bad |= ((uint32_t)al[kk][3] ^ vb1) & 1u;
            bad |= ((uint32_t)al[kk][5] ^ vb0) & 1u;
            bad |= ((uint32_t)al[kk][7] ^ vb1) & 1u;
          }
        }
        if (__all(bad == 0)) break;
        if (++attempts > (1 << 16)) break;            // failsafe
        if ((attempts & 7) == 7) __builtin_amdgcn_s_sleep(1);
        asm volatile("" : "+v"(pH), "+v"(pL));        // keep addrs live across retry
      }
    } else {
      if (t > 0 && lane == 0) {
        int spins = 0;
        while (poll_min8(pollbase) < (uint32_t)t) {
          if (++spins > 64) __builtin_amdgcn_s_sleep(1);
          if (spins > (1 << 20)) break;
        }
      }
      f4 a[8][2];
      #pragma unroll
      for (int kk = 0; kk < 8; ++kk) { a[kk][0] = (f4){0,0,0,0}; a[kk][1] = (f4){0,0,0,0}; }
      if (l15 < 8) {
        const float* hrow = (t ? (op - BH) : h0)
                            + (size_t)(rbase + l15) * HID + wave * 256 + kg * 8;
        #pragma unroll
        for (int kk = 0; kk < 8; ++kk) {
          llc_load_f4(a[kk][0], hrow + kk * 32);
          llc_load_f4(a[kk][1], hrow + kk * 32 + 4);
        }
      }
      WAIT_VM0();
      #pragma unroll
      for (int kk = 0; kk < 8; ++kk) cvt8(a[kk][0], a[kk][1], ah[kk], al[kk]);
    }

    f32x4 acc0 = {0,0,0,0}, acc1 = {0,0,0,0};
    #pragma unroll
    for (int kk = 0; kk < 8; ++kk) {
      const int k = wave * 256 + kk * 32 + kg * 8;
      const int si = (k ^ ((l15 & 7) << 3));
      short8 b0h = *(const short8*)(pHi + l15 * 1024 + si);
      short8 b0l = *(const short8*)(pLo + l15 * 1024 + si);
      short8 b1h = *(const short8*)(pHi + (16 + l15) * 1024 + si);
      short8 b1l = *(const short8*)(pLo + (16 + l15) * 1024 + si);
      acc0 = MFMA(ah[kk], b0h, acc0);
      acc0 = MFMA(al[kk], b0h, acc0);
      acc0 = MFMA(ah[kk], b0l, acc0);
      acc1 = MFMA(ah[kk], b1h, acc1);
      acc1 = MFMA(al[kk], b1h, acc1);
      acc1 = MFMA(ah[kk], b1l, acc1);
    }

    float* rb = red + buf_w * 2048;
    *(f32x4*)(rb + wave * 512 + lane * 4) = acc0;
    *(f32x4*)(rb + wave * 512 + 256 + lane * 4) = acc1;
    __syncthreads();

    if (wave == 0) {
      // lane owns (row er, tile-cols 4*ejc..+4); gather split-K partials
      f4 s;
      #pragma unroll
      for (int e = 0; e < 4; ++e) {
        const int tc = ejc * 4 + e;
        const int idx = (tc >> 4) * 256 + (((er >> 2) * 16 + (tc & 15)) * 4) + (er & 3);
        float a0 = rb[idx] + rb[512 + idx];
        float a1 = rb[1024 + idx] + rb[1536 + idx];
        s[e] = a0 + a1;
      }
      f4 hn;
      #pragma unroll
      for (int e = 0; e < 4; ++e) hn[e] = fmaxf(xv[e] + s[e] + bhv[e], 0.0f);
      #pragma unroll
      for (int e = 0; e < 4; ++e) hp[e] = 0.9f * hp[e] + 0.1f * hn[e];

      if (SPLIT) {
        // embed version (t+1)&3: short e==1 carries bit0, e==3 carries bit1;
        // hi LSB force is exactly compensated by lo (computed after forcing hi)
        const uint32_t wb0 = (uint32_t)((t + 1) & 1);
        const uint32_t wb1 = (uint32_t)(((t + 1) >> 1) & 1);
        short4v h4, l4;
        #pragma unroll
        for (int e = 0; e < 4; ++e) {
          float v = hp[e];
          uint32_t hb = bf16_rne(v);
          if (e == 1) hb = (hb & ~1u) | wb0;
          if (e == 3) hb = (hb & ~1u) | wb1;
          float hf = __uint_as_float(hb << 16);
          uint32_t lb = bf16_rne(v - hf);
          if (e == 1) lb = (lb & ~1u) | wb0;
          if (e == 3) lb = (lb & ~1u) | wb1;
          h4[e] = (short)hb; l4[e] = (short)lb;
        }
        uint16_t* bH = planes + ((pipe * 2 + buf_w) * 2 + 0) * PLANE_STRIDE
                       + er * HID + cg * 32 + ejc * 4;
        llc_store_s4(bH, h4);
        llc_store_s4(bH + PLANE_STRIDE, l4);
        // no flag, no ACK — the versioned data is the release
        // fp32 h off the critical path (plain cached; flushed at kernel end)
        *(f4*)(op + (size_t)(rbase + er) * HID + cg * 32 + ejc * 4) = hp;
        if (t == S_LEN - 1)
          *(f4*)(out + (size_t)S_LEN * BH + (size_t)(rbase + er) * HID + cg * 32 + ejc * 4) = hp;
      } else {
        llc_store_f4(op + (size_t)(rbase + er) * HID + cg * 32 + ejc * 4, hp);
        asm volatile("s_waitcnt vmcnt(0)" ::: "memory");   // fallback keeps ACK
        if (lane == 0) llc_store_u32(myflag, (uint32_t)(t + 1));
        if (t == S_LEN - 1)
          llc_store_f4(out + (size_t)S_LEN * BH + (size_t)(rbase + er) * HID + cg * 32 + ejc * 4, hp);
      }
    }
  }
}

extern "C" void kernel_launch(void* const* d_in, const int* in_sizes, int n_in,
                              void* d_out, int out_size, void* d_ws, size_t ws_size,
                              hipStream_t stream) {
  (void)in_sizes; (void)n_in; (void)out_size;
  const float* x  = (const float*)d_in[0];
  const float* h0 = (const float*)d_in[1];
  const float* Wx = (const float*)d_in[2];
  const float* bx = (const float*)d_in[3];
  const float* Wh = (const float*)d_in[4];
  const float* bh = (const float*)d_in[5];
  float* out = (float*)d_out;
  uint32_t* ws = (uint32_t*)d_ws;

  ctrnn_init<<<1, 256, 0, stream>>>(ws);
  if (ws_size >= (size_t)WS_NEEDED) {
    hipFuncSetAttribute((const void*)ctrnn_main<true>,
                        hipFuncAttributeMaxDynamicSharedMemorySize, SMEM_BYTES);
    ctrnn_main<true><<<256, 256, SMEM_BYTES, stream>>>(x, h0, Wx, bx, Wh, bh, out, ws);
  } else {
    hipFuncSetAttribute((const void*)ctrnn_main<false>,
                        hipFuncAttributeMaxDynamicSharedMemorySize, SMEM_BYTES);
    ctrnn_main<false><<<256, 256, SMEM_BYTES, stream>>>(x, h0, Wx, bx, Wh, bh, out, ws);
  }
}

// Round 14
// 2010.964 us; speedup vs baseline: 1.3617x; 1.3617x over previous
//
#include <hip/hip_runtime.h>
#include <stdint.h>

#define S_LEN 512
#define BATCH 64
#define INSZ  256
#define HID   1024
#define BH    (BATCH*HID)          // 65536
#define NPIPE 8
#define ROWSP 8                    // batch rows per pipeline
#define NCG   32                   // WGs per pipeline
// LDS: 64KB Wh-hi + 64KB Wh-lo + 2x8KB reduce (dbuf)
#define SMEM_BYTES (131072 + 16384)
// ws dword map:
//  [0,1024)  flags: flag(pipe,cg) at dword pipe*128 + (cg>>3)*32 + (cg&7)
//            (each wave's 8-producer poll set = private 32B group). gbar at ws[8].
//  byte 4096+: bf16 planes. chunk idx (pipe*2+buf)*2+plane ; lo = hi+PLANE_STRIDE
#define WS_PLANES_OFF 4096
#define PLANE_STRIDE (ROWSP*HID)   // 8192 shorts
#define WS_NEEDED (WS_PLANES_OFF + NPIPE*2*2*PLANE_STRIDE*2)   // 528384 B
#define FLAG_IDX(p, c) ((p)*128 + ((c)>>3)*32 + ((c)&7))

typedef __attribute__((ext_vector_type(8))) short short8;   // 8 bf16
typedef __attribute__((ext_vector_type(4))) short short4v;
typedef __attribute__((ext_vector_type(4))) float f32x4;
typedef __attribute__((ext_vector_type(4))) float f4;
typedef __attribute__((ext_vector_type(4))) unsigned int u32x4;

__device__ __forceinline__ uint32_t bf16_rne(float x) {
  uint32_t u = __float_as_uint(x);
  return (u + 0x7fffu + ((u >> 16) & 1u)) >> 16;
}
__device__ __forceinline__ void cvt_pair(float v, short& h, short& l) {
  uint32_t hb = bf16_rne(v);
  float hf = __uint_as_float(hb << 16);
  uint32_t lb = bf16_rne(v - hf);
  h = (short)hb; l = (short)lb;
}
__device__ __forceinline__ void cvt8(f4 a0, f4 a1, short8& hi, short8& lo) {
  #pragma unroll
  for (int e = 0; e < 4; ++e) { short h, l; cvt_pair(a0[e], h, l); hi[e] = h; lo[e] = l; }
  #pragma unroll
  for (int e = 0; e < 4; ++e) { short h, l; cvt_pair(a1[e], h, l); hi[4+e] = h; lo[4+e] = l; }
}

#define MFMA(A, B, C) __builtin_amdgcn_mfma_f32_16x16x32_bf16((A), (B), (C), 0, 0, 0)
#define WAIT_VM0() do { asm volatile("s_waitcnt vmcnt(0)" ::: "memory"); \
                        __builtin_amdgcn_sched_barrier(0); } while (0)

// ---------- LLC-direct (bypass L1+L2, MALL coherence point) helpers ----------
__device__ __forceinline__ void llc_load_f4(f4& d, const float* p) {
  asm volatile("global_load_dwordx4 %0, %1, off sc0 sc1" : "=v"(d) : "v"(p) : "memory");
}
__device__ __forceinline__ void llc_load_s8(short8& d, const uint16_t* p) {
  asm volatile("global_load_dwordx4 %0, %1, off sc0 sc1" : "=v"(d) : "v"(p) : "memory");
}
__device__ __forceinline__ void llc_store_f1(float* p, float v) {
  asm volatile("global_store_dword %0, %1, off sc0 sc1" :: "v"(p), "v"(v) : "memory");
}
__device__ __forceinline__ void llc_store_u16(uint16_t* p, uint32_t v) {
  asm volatile("global_store_short %0, %1, off sc0 sc1" :: "v"(p), "v"(v) : "memory");
}
__device__ __forceinline__ void llc_store_u32(uint32_t* p, uint32_t v) {
  asm volatile("global_store_dword %0, %1, off sc0 sc1" :: "v"(p), "v"(v) : "memory");
}
__device__ __forceinline__ uint32_t poll_min8(const uint32_t* p) {
  u32x4 a, b;
  asm volatile("global_load_dwordx4 %0, %2, off sc0 sc1\n\t"
               "global_load_dwordx4 %1, %2, off offset:16 sc0 sc1\n\t"
               "s_waitcnt vmcnt(0)"
               : "=&v"(a), "=&v"(b) : "v"(p) : "memory");
  uint32_t m = a.x;
  m = a.y < m ? a.y : m;  m = a.z < m ? a.z : m;  m = a.w < m ? a.w : m;
  m = b.x < m ? b.x : m;  m = b.y < m ? b.y : m;  m = b.z < m ? b.z : m;
  m = b.w < m ? b.w : m;
  return m;
}

__global__ void ctrnn_init(uint32_t* ws) {
  const int i = threadIdx.x;
  ws[i] = 0; ws[i + 256] = 0; ws[i + 512] = 0; ws[i + 768] = 0;
}

template<bool SPLIT>
__global__ __launch_bounds__(256, 1)
void ctrnn_main(const float* __restrict__ x,  const float* __restrict__ h0,
                const float* __restrict__ Wx, const float* __restrict__ bx,
                const float* __restrict__ Wh, const float* __restrict__ bh,
                float* __restrict__ out, uint32_t* ws)
{
  extern __shared__ char smem_raw[];
  short* pHi = (short*)smem_raw;             // 64KB
  short* pLo = pHi + 32768;                  // 64KB
  float* red = (float*)(smem_raw + 131072);  // 2 x 8KB (dbuf by t&1)

  const int tid  = threadIdx.x;
  const int wg   = blockIdx.x;
  const int lane = tid & 63;
  const int wave = tid >> 6;
  const int l15  = lane & 15;
  const int kg   = lane >> 4;

  // ======================= phase 0: xproj = x @ Wx^T + bx =======================
  for (int tt = 0; tt < 2; ++tt) {
    const int t = wg * 2 + tt;
    if (tt) __syncthreads();
    { // stage x[t] (64x256 f32) into swizzled split hi/lo bf16 planes
      const float* xt = x + (size_t)t * (BATCH * INSZ);
      #pragma unroll
      for (int it = 0; it < 16; ++it) {
        const int flat4 = (it * 256 + tid) * 4;
        const int b = flat4 >> 8;
        const int k = flat4 & 255;
        f4 v = *(const f4*)(xt + b * INSZ + k);
        short4v hv, lv;
        #pragma unroll
        for (int e = 0; e < 4; ++e) { short h, l; cvt_pair(v[e], h, l); hv[e] = h; lv[e] = l; }
        const int si = b * 256 + (k ^ ((b & 7) << 3));
        *(short4v*)(pHi + si) = hv;
        *(short4v*)(pLo + si) = lv;
      }
    }
    __syncthreads();
    for (int ntl = 0; ntl < 16; ++ntl) {
      const int nt = wave * 16 + ntl;
      const int nn = nt * 16 + l15;
      f32x4 acc0 = {0,0,0,0}, acc1 = {0,0,0,0}, acc2 = {0,0,0,0}, acc3 = {0,0,0,0};
      #pragma unroll
      for (int kt = 0; kt < 8; ++kt) {
        const int k = kt * 32 + kg * 8;
        const float* wp = Wx + (size_t)nn * INSZ + k;
        short8 bhi8, blo8;
        cvt8(*(const f4*)wp, *(const f4*)(wp + 4), bhi8, blo8);
        const int swz = (l15 & 7) << 3;
        short8 a0h = *(const short8*)(pHi + (     l15) * 256 + (k ^ swz));
        short8 a0l = *(const short8*)(pLo + (     l15) * 256 + (k ^ swz));
        short8 a1h = *(const short8*)(pHi + (16 + l15) * 256 + (k ^ swz));
        short8 a1l = *(const short8*)(pLo + (16 + l15) * 256 + (k ^ swz));
        short8 a2h = *(const short8*)(pHi + (32 + l15) * 256 + (k ^ swz));
        short8 a2l = *(const short8*)(pLo + (32 + l15) * 256 + (k ^ swz));
        short8 a3h = *(const short8*)(pHi + (48 + l15) * 256 + (k ^ swz));
        short8 a3l = *(const short8*)(pLo + (48 + l15) * 256 + (k ^ swz));
        acc0 = MFMA(a0h, bhi8, acc0);
        acc1 = MFMA(a1h, bhi8, acc1);
        acc2 = MFMA(a2h, bhi8, acc2);
        acc3 = MFMA(a3h, bhi8, acc3);
        acc0 = MFMA(a0l, bhi8, acc0);
        acc1 = MFMA(a1l, bhi8, acc1);
        acc2 = MFMA(a2l, bhi8, acc2);
        acc3 = MFMA(a3l, bhi8, acc3);
        acc0 = MFMA(a0h, blo8, acc0);
        acc1 = MFMA(a1h, blo8, acc1);
        acc2 = MFMA(a2h, blo8, acc2);
        acc3 = MFMA(a3h, blo8, acc3);
      }
      const float bxn = bx[nn];
      float* op = out + (size_t)t * BH;
      #pragma unroll
      for (int i = 0; i < 4; ++i) {
        const int b0 = kg * 4 + i;
        op[(size_t)(     b0) * HID + nn] = acc0[i] + bxn;
        op[(size_t)(16 + b0) * HID + nn] = acc1[i] + bxn;
        op[(size_t)(32 + b0) * HID + nn] = acc2[i] + bxn;
        op[(size_t)(48 + b0) * HID + nn] = acc3[i] + bxn;
      }
    }
  }

  // ======================= load Wh slice (32 cols x 1024 K) into LDS =======================
  __syncthreads();
  const int pipe = wg >> 5;             // 0..7  : batch rows [8*pipe, 8*pipe+8)
  const int cg   = wg & 31;             // 0..31 : cols [32*cg, 32*cg+32)
  const int rbase = pipe * ROWSP;
  #pragma unroll
  for (int it = 0; it < 32; ++it) {
    const int flat4 = (it * 256 + tid) * 4;
    const int r = flat4 >> 10;
    const int k = flat4 & 1023;
    f4 w = *(const f4*)(Wh + (size_t)(cg * 32 + r) * HID + k);
    short4v hv, lv;
    #pragma unroll
    for (int e = 0; e < 4; ++e) { short h, l; cvt_pair(w[e], h, l); hv[e] = h; lv[e] = l; }
    const int si = r * 1024 + (k ^ ((r & 7) << 3));
    *(short4v*)(pHi + si) = hv;
    *(short4v*)(pLo + si) = lv;
  }

  uint16_t* planes = (uint16_t*)((char*)ws + WS_PLANES_OFF);
  // chunk base (shorts): ((pipe*2 + buf)*2 + plane) * PLANE_STRIDE ; lo = hi + PLANE_STRIDE

  // per-thread output ownership: row er2 = tid>>5 (0..7), col ec2 = tid&31 (0..31)
  const int er2 = tid >> 5, ec2 = tid & 31;
  const int gcol = cg * 32 + ec2;

  // pre-stage h0 tile into planes buf=1 (read at t=0) with version bits = 0
  // (cols c&3==1 carry bit0, c&3==3 carry bit1); ordered by the global barrier
  if (SPLIT) {
    const float v = h0[(size_t)(rbase + er2) * HID + gcol];
    uint32_t hb = bf16_rne(v);
    const bool vb = ((ec2 & 3) == 1) || ((ec2 & 3) == 3);
    if (vb) hb &= ~1u;
    float hf = __uint_as_float(hb << 16);
    uint32_t lb = bf16_rne(v - hf);
    if (vb) lb &= ~1u;
    uint16_t* bH = planes + ((pipe * 2 + 1) * 2 + 0) * PLANE_STRIDE + er2 * HID + gcol;
    llc_store_u16(bH, hb & 0xffffu);
    llc_store_u16(bH + PLANE_STRIDE, lb & 0xffffu);
  }

  // per-thread epilogue state
  float hp  = h0[(size_t)(rbase + er2) * HID + gcol];
  const float bhc = bh[gcol];

  // drain h0-staging LLC stores from ALL waves before any WG can pass the barrier
  asm volatile("s_waitcnt vmcnt(0)" ::: "memory");
  __syncthreads();

  // ======================= global barrier (release flushes phase-0 stores) ==========
  uint32_t* gbar = ws + 8;
  if (tid == 0) {
    __hip_atomic_fetch_add(gbar, 1u, __ATOMIC_RELEASE, __HIP_MEMORY_SCOPE_AGENT);
    int spins = 0;
    while (__hip_atomic_load(gbar, __ATOMIC_RELAXED, __HIP_MEMORY_SCOPE_AGENT) < 256u) {
      __builtin_amdgcn_s_sleep(8);
      if (++spins > (1 << 20)) break;   // failsafe: wrong answer beats eternal hang
    }
  }
  __syncthreads();
  __builtin_amdgcn_fence(__ATOMIC_ACQUIRE, "agent");

  // ======================= scan =======================
  uint32_t* flags = ws;
  uint32_t* myflag = flags + FLAG_IDX(pipe, cg);
  const uint32_t* pollbase = flags + pipe * 128 + wave * 32;
  // reduce-gather index for this thread's (er2, ec2)
  const int gidx = (ec2 >> 4) * 256 + (((er2 >> 2) * 16 + (ec2 & 15)) * 4) + (er2 & 3);

  for (int t = 0; t < S_LEN; ++t) {
    float* op = out + (size_t)t * BH;
    const int buf_r = (t + 1) & 1, buf_w = t & 1;

    // epilogue xproj operand (plain cached load; compiler inserts waitcnt at use)
    const float xvs = op[(size_t)(rbase + er2) * HID + gcol];

    // per-wave gate FIRST (cheap discovery + union over 4 waves = all-32 backpressure)
    if (t > 0 && lane == 0) {
      int spins = 0;
      while (poll_min8(pollbase) < (uint32_t)t) {
        if (++spins > 64) __builtin_amdgcn_s_sleep(1);
        if (spins > (1 << 20)) break;    // failsafe
      }
    }

    short8 ah[8], al[8];
    #pragma unroll
    for (int kk = 0; kk < 8; ++kk) { ah[kk] = (short8)0; al[kk] = (short8)0; }

    if (SPLIT) {
      // A-loads AFTER the gate; verify embedded version bits (flag is a hint;
      // version bits are the truth — retries expected ~never)
      const uint16_t* pH = planes + ((pipe * 2 + buf_r) * 2 + 0) * PLANE_STRIDE
                           + l15 * HID + wave * 256 + kg * 8;
      const uint16_t* pL = pH + PLANE_STRIDE;
      const uint32_t vb0 = (uint32_t)(t & 1);
      const uint32_t vb1 = (uint32_t)((t >> 1) & 1);
      int attempts = 0;
      for (;;) {
        if (l15 < 8) {
          #pragma unroll
          for (int kk = 0; kk < 8; ++kk) {
            llc_load_s8(ah[kk], pH + kk * 32);
            llc_load_s8(al[kk], pL + kk * 32);
          }
        }
        WAIT_VM0();
        uint32_t bad = 0;
        if (l15 < 8) {
          #pragma unroll
          for (int kk = 0; kk < 8; ++kk) {
            bad |= ((uint32_t)ah[kk][1] ^ vb0) & 1u;
            bad |= ((uint32_t)ah[kk][3] ^ vb1) & 1u;
            bad |= ((uint32_t)ah[kk][5] ^ vb0) & 1u;
            bad |= ((uint32_t)ah[kk][7] ^ vb1) & 1u;
            bad |= ((uint32_t)al[kk][1] ^ vb0) & 1u;
            bad |= ((uint32_t)al[kk][3] ^ vb1) & 1u;
            bad |= ((uint32_t)al[kk][5] ^ vb0) & 1u;
            bad |= ((uint32_t)al[kk][7] ^ vb1) & 1u;
          }
        }
        if (__all(bad == 0)) break;
        if (++attempts > (1 << 16)) break;            // failsafe
        if ((attempts & 3) == 3) __builtin_amdgcn_s_sleep(1);
        asm volatile("" : "+v"(pH), "+v"(pL));        // keep addrs live across retry
      }
    } else {
      f4 a[8][2];
      #pragma unroll
      for (int kk = 0; kk < 8; ++kk) { a[kk][0] = (f4){0,0,0,0}; a[kk][1] = (f4){0,0,0,0}; }
      if (l15 < 8) {
        const float* hrow = (t ? (op - BH) : h0)
                            + (size_t)(rbase + l15) * HID + wave * 256 + kg * 8;
        #pragma unroll
        for (int kk = 0; kk < 8; ++kk) {
          llc_load_f4(a[kk][0], hrow + kk * 32);
          llc_load_f4(a[kk][1], hrow + kk * 32 + 4);
        }
      }
      WAIT_VM0();
      #pragma unroll
      for (int kk = 0; kk < 8; ++kk) cvt8(a[kk][0], a[kk][1], ah[kk], al[kk]);
    }

    f32x4 acc0 = {0,0,0,0}, acc1 = {0,0,0,0};
    #pragma unroll
    for (int kk = 0; kk < 8; ++kk) {
      const int k = wave * 256 + kk * 32 + kg * 8;
      const int si = (k ^ ((l15 & 7) << 3));
      short8 b0h = *(const short8*)(pHi + l15 * 1024 + si);
      short8 b0l = *(const short8*)(pLo + l15 * 1024 + si);
      short8 b1h = *(const short8*)(pHi + (16 + l15) * 1024 + si);
      short8 b1l = *(const short8*)(pLo + (16 + l15) * 1024 + si);
      acc0 = MFMA(ah[kk], b0h, acc0);
      acc0 = MFMA(al[kk], b0h, acc0);
      acc0 = MFMA(ah[kk], b0l, acc0);
      acc1 = MFMA(ah[kk], b1h, acc1);
      acc1 = MFMA(al[kk], b1h, acc1);
      acc1 = MFMA(ah[kk], b1l, acc1);
    }

    float* rb = red + buf_w * 2048;
    *(f32x4*)(rb + wave * 512 + lane * 4) = acc0;
    *(f32x4*)(rb + wave * 512 + 256 + lane * 4) = acc1;
    __syncthreads();

    // EARLY FLAG (SPLIT only): safe — backpressure needs only "done reading
    // step-t", true at this barrier; data freshness is certified by version bits.
    if (SPLIT && tid == 0) llc_store_u32(myflag, (uint32_t)(t + 1));

    // ---- all-thread epilogue: 1 output per thread (row er2, col ec2) ----
    {
      const float s = rb[gidx] + rb[512 + gidx] + rb[1024 + gidx] + rb[1536 + gidx];
      const float hn = fmaxf(xvs + s + bhc, 0.0f);
      hp = 0.9f * hp + 0.1f * hn;

      if (SPLIT) {
        const uint32_t wb0 = (uint32_t)((t + 1) & 1);
        const uint32_t wb1 = (uint32_t)(((t + 1) >> 1) & 1);
        uint32_t hb = bf16_rne(hp);
        if ((ec2 & 3) == 1) hb = (hb & ~1u) | wb0;
        else if ((ec2 & 3) == 3) hb = (hb & ~1u) | wb1;
        float hf = __uint_as_float(hb << 16);
        uint32_t lb = bf16_rne(hp - hf);
        if ((ec2 & 3) == 1) lb = (lb & ~1u) | wb0;
        else if ((ec2 & 3) == 3) lb = (lb & ~1u) | wb1;
        uint16_t* bH = planes + ((pipe * 2 + buf_w) * 2 + 0) * PLANE_STRIDE
                       + er2 * HID + gcol;
        llc_store_u16(bH, hb & 0xffffu);
        llc_store_u16(bH + PLANE_STRIDE, lb & 0xffffu);
        // fp32 h off the critical path (plain cached; flushed at kernel end)
        op[(size_t)(rbase + er2) * HID + gcol] = hp;
        if (t == S_LEN - 1)
          out[(size_t)S_LEN * BH + (size_t)(rbase + er2) * HID + gcol] = hp;
      } else {
        llc_store_f1(op + (size_t)(rbase + er2) * HID + gcol, hp);
        asm volatile("s_waitcnt vmcnt(0)" ::: "memory");   // per-wave drain
        __syncthreads();                                   // all stores at MALL
        if (tid == 0) llc_store_u32(myflag, (uint32_t)(t + 1));
        if (t == S_LEN - 1)
          llc_store_f1(out + (size_t)S_LEN * BH + (size_t)(rbase + er2) * HID + gcol, hp);
      }
    }
  }
}

extern "C" void kernel_launch(void* const* d_in, const int* in_sizes, int n_in,
                              void* d_out, int out_size, void* d_ws, size_t ws_size,
                              hipStream_t stream) {
  (void)in_sizes; (void)n_in; (void)out_size;
  const float* x  = (const float*)d_in[0];
  const float* h0 = (const float*)d_in[1];
  const float* Wx = (const float*)d_in[2];
  const float* bx = (const float*)d_in[3];
  const float* Wh = (const float*)d_in[4];
  const float* bh = (const float*)d_in[5];
  float* out = (float*)d_out;
  uint32_t* ws = (uint32_t*)d_ws;

  ctrnn_init<<<1, 256, 0, stream>>>(ws);
  if (ws_size >= (size_t)WS_NEEDED) {
    hipFuncSetAttribute((const void*)ctrnn_main<true>,
                        hipFuncAttributeMaxDynamicSharedMemorySize, SMEM_BYTES);
    ctrnn_main<true><<<256, 256, SMEM_BYTES, stream>>>(x, h0, Wx, bx, Wh, bh, out, ws);
  } else {
    hipFuncSetAttribute((const void*)ctrnn_main<false>,
                        hipFuncAttributeMaxDynamicSharedMemorySize, SMEM_BYTES);
    ctrnn_main<false><<<256, 256, SMEM_BYTES, stream>>>(x, h0, Wx, bx, Wh, bh, out, ws);
  }
}